// Round 5
// baseline (512.775 us; speedup 1.0000x reference)
//
#include <hip/hip_runtime.h>

#define B_ROWS   131072
#define MTILE    64
#define KCHUNKS  17        // 544 / 32
#define LDA      552       // At leading dim f16: 544+8 pad
#define LDX      528       // X2 leading dim f16: 512+16 pad
// ws layout: [0,128KB) mask u8; [128KB,+557056) W1f f16 [544 frags][512]; then W2f f16 [16][512]
#define W1F_OFF  ((size_t)B_ROWS)
#define W2F_OFF  (W1F_OFF + (size_t)544 * 512 * 2)

typedef _Float16 f16x8 __attribute__((ext_vector_type(8)));
typedef float    f32x4 __attribute__((ext_vector_type(4)));

__device__ inline unsigned short f2h(float f) {
  _Float16 h = (_Float16)f;
  return __builtin_bit_cast(unsigned short, h);
}
__device__ inline float h2f(unsigned short u) {
  return (float)__builtin_bit_cast(_Float16, u);
}
__device__ inline float selu_f(float x) {
  const float lam = 1.0507009873554805f, alp = 1.6732632423543772f;
  return x > 0.f ? lam * x : lam * alp * (__expf(x) - 1.f);
}

__global__ void scatter_mask(const int* __restrict__ coords,
                             unsigned char* __restrict__ mask) {
  int i = blockIdx.x * 256 + threadIdx.x;
  mask[coords[i]] = 1u;
}

// Blocks 0..543: W1 fp32 [526][512] -> W1f f16 pre-fragmented, per-wave MFMA order:
//   frag = (wq*17 + c)*4 + ni;  W1f[frag*512 + lane*8 + e] = W1[k-perm][n]
//   n = wq*64+ni*16+(lane&15), k = c*32+(lane>>4)*8+e
//   K-perm: k<512 -> orig row k+14; 512<=k<526 -> jnt rows k-512; else 0.
// Blocks 544..559: W2 fp32 [512][7] -> W2f f16 [16 kchunks][512], n padded to 16.
__global__ void build_wf(const float* __restrict__ W1, const float* __restrict__ W2,
                         unsigned short* __restrict__ W1f, unsigned short* __restrict__ W2f) {
  int tid = threadIdx.x;               // 0..511
  if (blockIdx.x < 544) {
    int fragIdx = blockIdx.x;
    int ni = fragIdx & 3;
    int c  = (fragIdx >> 2) % 17;
    int wq = fragIdx / 68;
    int nbase = wq * 64 + ni * 16;
    __shared__ float t[32][17];        // [k_local][n_local], +1 pad
    int kl = tid >> 4, nl = tid & 15;  // coalesced read: consecutive tid -> consecutive n
    int kg = c * 32 + kl;
    float v = 0.f;
    if (kg < 512)      v = W1[(size_t)(kg + 14) * 512 + nbase + nl];
    else if (kg < 526) v = W1[(size_t)(kg - 512) * 512 + nbase + nl];
    t[kl][nl] = v;
    __syncthreads();
    int lane = tid >> 3, e = tid & 7;
    int k2 = ((lane >> 4) & 3) * 8 + e;
    int n2 = lane & 15;
    W1f[(size_t)fragIdx * 512 + tid] = f2h(t[k2][n2]);
  } else {
    int c2 = blockIdx.x - 544;         // 0..15
    int lane = tid >> 3, e = tid & 7;
    int n = lane & 15, quad = (lane >> 4) & 3;
    int k = c2 * 32 + quad * 8 + e;
    float v = (n < 7) ? W2[(size_t)k * 7 + n] : 0.f;
    W2f[(size_t)c2 * 512 + tid] = f2h(v);
  }
}

struct __align__(16) SMem {
  // union: At[64][552] f16 = 70656B (K loop)
  //        X2[64][528] f16 = 67584B + O[64][8] f32 = 2048B -> 69632B (epilogue)
  char buf[70656];
  float part[8][MTILE][2];   // per-wave LN2 partial s,q
  float mean2[MTILE], rstd2[MTILE];
};

__global__ __launch_bounds__(512, 4) void actor_main(
    const float* __restrict__ feat, const unsigned char* __restrict__ mask,
    const float* __restrict__ jp, const float* __restrict__ jg,
    const float* __restrict__ ln1g, const float* __restrict__ ln1b,
    const unsigned short* __restrict__ W1f, const float* __restrict__ b1,
    const float* __restrict__ ln2g, const float* __restrict__ ln2b,
    const unsigned short* __restrict__ W2f, const float* __restrict__ b2,
    float* __restrict__ out) {
  __shared__ SMem sm;
  unsigned short* At = (unsigned short*)sm.buf;            // [64][LDA] f16
  unsigned short* X2 = (unsigned short*)sm.buf;            // [64][LDX] f16 (epilogue union)
  float*          O  = (float*)(sm.buf + 64 * LDX * 2);    // [64][8] f32

  const int tid  = threadIdx.x;
  const int wq   = tid >> 6;   // wave 0..7 = N-slice (64 cols each)
  const int lane = tid & 63;
  const int m0   = blockIdx.x * MTILE;
  const int mrow = lane & 15;
  const int quad = lane >> 4;

  // ---------- A build pass 1: stream feat -> raw(f*mk) f16 in At, accumulate stats ----------
  // thread (arow=tid>>3, acg=tid&7): row m0+arow, cols {c*32+acg*4..+4}. No big reg array.
  const int arow = tid >> 3;
  const int acg  = tid & 7;
  {
    const int row  = m0 + arow;
    float mk = mask[row] ? 1.f : 0.f;  // masked-out row => y=0 => LN -> b -> selu(b)
    const float4* frow = (const float4*)feat + (size_t)row * 128 + acg;
    float s = 0.f, q = 0.f;
#pragma unroll
    for (int c = 0; c < 16; ++c) {
      float4 v = frow[(size_t)c * 8];
      s += v.x + v.y + v.z + v.w;
      q += v.x * v.x + v.y * v.y + v.z * v.z + v.w * v.w;
      union { unsigned short us[4]; uint2 u; } pk;
      pk.us[0] = f2h(v.x * mk); pk.us[1] = f2h(v.y * mk);
      pk.us[2] = f2h(v.z * mk); pk.us[3] = f2h(v.w * mk);
      *(uint2*)&At[arow * LDA + c * 32 + acg * 4] = pk.u;
    }
    {  // jnt chunk: cols 512..543 (jp[0..7), jg[7..14), zero pad) -- raw, no LN
      union { unsigned short us[4]; uint2 u; } pk;
#pragma unroll
      for (int q2 = 0; q2 < 4; ++q2) {
        int kk = acg * 4 + q2;
        float val = 0.f;
        if (kk < 7)       val = jp[(size_t)row * 7 + kk];
        else if (kk < 14) val = jg[(size_t)row * 7 + kk - 7];
        pk.us[q2] = f2h(val);
      }
      *(uint2*)&At[arow * LDA + 512 + acg * 4] = pk.u;
    }
    // row stats across the 8 lanes sharing this row
    s += __shfl_xor(s, 1); q += __shfl_xor(q, 1);
    s += __shfl_xor(s, 2); q += __shfl_xor(q, 2);
    s += __shfl_xor(s, 4); q += __shfl_xor(q, 4);
    float mean = mk * s * (1.f / 512.f);
    float msq  = mk * q * (1.f / 512.f);
    float rstd = rsqrtf(msq - mean * mean + 1e-5f);

    // ---------- pass 2: read back own chunks, apply LN1+SELU, write back ----------
#pragma unroll
    for (int c = 0; c < 16; ++c) {
      union { unsigned short us[4]; uint2 u; } w;
      w.u = *(uint2*)&At[arow * LDA + c * 32 + acg * 4];
      float4 g = ((const float4*)ln1g)[c * 8 + acg];
      float4 b = ((const float4*)ln1b)[c * 8 + acg];
      union { unsigned short us[4]; uint2 u; } pk;
      pk.us[0] = f2h(selu_f((h2f(w.us[0]) - mean) * rstd * g.x + b.x));
      pk.us[1] = f2h(selu_f((h2f(w.us[1]) - mean) * rstd * g.y + b.y));
      pk.us[2] = f2h(selu_f((h2f(w.us[2]) - mean) * rstd * g.z + b.z));
      pk.us[3] = f2h(selu_f((h2f(w.us[3]) - mean) * rstd * g.w + b.w));
      *(uint2*)&At[arow * LDA + c * 32 + acg * 4] = pk.u;
    }
  }

  // ---------- B chunk-0 prefetch (after A-build so its regs don't pressure pass 1) ----------
  const unsigned short* wBase = W1f + (size_t)wq * 68 * 512 + lane * 8;
  f16x8 bE[4], bO[4];
#pragma unroll
  for (int ni = 0; ni < 4; ++ni)
    bE[ni] = *(const f16x8*)(wBase + (size_t)ni * 512);

  __syncthreads();  // barrier #1 (only one before K loop)

  // ---------- K loop: barrier-free, pre-fragmented B, reg ping-pong ----------
  f32x4 acc[4][4];
#pragma unroll
  for (int mi = 0; mi < 4; ++mi)
#pragma unroll
    for (int ni = 0; ni < 4; ++ni) acc[mi][ni] = (f32x4){0.f, 0.f, 0.f, 0.f};

  const unsigned short* aB = At + mrow * LDA + quad * 8;

  auto loadB = [&](f16x8* dst, int c) {
#pragma unroll
    for (int ni = 0; ni < 4; ++ni)
      dst[ni] = *(const f16x8*)(wBase + (size_t)(c * 4 + ni) * 512);
  };
  auto step = [&](const f16x8* bF, int c) {
    f16x8 a[4];
#pragma unroll
    for (int mi = 0; mi < 4; ++mi)
      a[mi] = *(const f16x8*)(aB + mi * 16 * LDA + c * 32);
#pragma unroll
    for (int mi = 0; mi < 4; ++mi)
#pragma unroll
      for (int ni = 0; ni < 4; ++ni)
        acc[mi][ni] = __builtin_amdgcn_mfma_f32_16x16x32_f16(a[mi], bF[ni], acc[mi][ni], 0, 0, 0);
  };

  for (int c = 0; c < KCHUNKS - 1; c += 2) {  // c = 0,2,...,14
    loadB(bO, c + 1);
    step(bE, c);
    loadB(bE, c + 2);                         // c+2 <= 16, valid
    step(bO, c + 1);
  }
  step(bE, 16);

  // ---------- GEMM2 B-frag prefetch (wave's own K-slice k = wq*64..+64) ----------
  f16x8 bW2[2];
  bW2[0] = *(const f16x8*)&W2f[(size_t)(2 * wq)     * 512 + lane * 8];
  bW2[1] = *(const f16x8*)&W2f[(size_t)(2 * wq + 1) * 512 + lane * 8];

  // ---------- epilogue: +b1, LN2 stats (per-wave partials, no atomics) ----------
  float b1v[4], g2v[4], bl2v[4];
#pragma unroll
  for (int ni = 0; ni < 4; ++ni) {
    int col = wq * 64 + ni * 16 + mrow;
    b1v[ni] = b1[col]; g2v[ni] = ln2g[col]; bl2v[ni] = ln2b[col];
  }
#pragma unroll
  for (int mi = 0; mi < 4; ++mi)
#pragma unroll
    for (int reg = 0; reg < 4; ++reg) {
      int r = mi * 16 + quad * 4 + reg;  // C/D layout: col=lane&15, row=quad*4+reg
      float s = 0.f, q = 0.f;
#pragma unroll
      for (int ni = 0; ni < 4; ++ni) {
        float v = acc[mi][ni][reg] + b1v[ni];
        acc[mi][ni][reg] = v;
        s += v; q += v * v;
      }
      s += __shfl_xor(s, 1); q += __shfl_xor(q, 1);
      s += __shfl_xor(s, 2); q += __shfl_xor(q, 2);
      s += __shfl_xor(s, 4); q += __shfl_xor(q, 4);
      s += __shfl_xor(s, 8); q += __shfl_xor(q, 8);
      if ((lane & 15) == 0) { sm.part[wq][r][0] = s; sm.part[wq][r][1] = q; }
    }
  __syncthreads();  // barrier #2: K-loop At reads done; partials complete
  if (tid < MTILE) {
    float s = 0.f, q = 0.f;
#pragma unroll
    for (int w = 0; w < 8; ++w) { s += sm.part[w][tid][0]; q += sm.part[w][tid][1]; }
    float mean = s * (1.f / 512.f);
    float var  = q * (1.f / 512.f) - mean * mean;
    sm.mean2[tid] = mean;
    sm.rstd2[tid] = rsqrtf(var + 1e-5f);
  }
  O[tid] = 0.f;     // 64x8 = 512 floats, region beyond X2, At dead
  __syncthreads();  // barrier #3: mean2/rstd2 + O ready
#pragma unroll
  for (int mi = 0; mi < 4; ++mi)
#pragma unroll
    for (int ni = 0; ni < 4; ++ni)
#pragma unroll
      for (int reg = 0; reg < 4; ++reg) {
        int r = mi * 16 + quad * 4 + reg;
        int col = wq * 64 + ni * 16 + mrow;
        float v = (acc[mi][ni][reg] - sm.mean2[r]) * sm.rstd2[r] * g2v[ni] + bl2v[ni];
        X2[r * LDX + col] = f2h(selu_f(v));
      }
  __syncthreads();  // barrier #4: X2 complete

  // ---------- GEMM2 (512->7) via MFMA, K-split across waves, LDS f32 reduce ----------
  {
    f32x4 acc2[4];
#pragma unroll
    for (int mi = 0; mi < 4; ++mi) acc2[mi] = (f32x4){0.f, 0.f, 0.f, 0.f};
#pragma unroll
    for (int j = 0; j < 2; ++j) {
      int c2 = 2 * wq + j;
#pragma unroll
      for (int mi = 0; mi < 4; ++mi) {
        f16x8 a = *(const f16x8*)&X2[(mi * 16 + mrow) * LDX + c2 * 32 + quad * 8];
        acc2[mi] = __builtin_amdgcn_mfma_f32_16x16x32_f16(a, bW2[j], acc2[mi], 0, 0, 0);
      }
    }
#pragma unroll
    for (int mi = 0; mi < 4; ++mi)
#pragma unroll
      for (int reg = 0; reg < 4; ++reg)
        if (mrow < 7)
          atomicAdd(&O[(mi * 16 + quad * 4 + reg) * 8 + mrow], acc2[mi][reg]);
  }
  __syncthreads();  // barrier #5: O complete
  {
    int r = tid >> 3, c = tid & 7;
    if (c < 7)
      out[(size_t)(m0 + r) * 7 + c] = tanhf(O[tid] + b2[c]);
  }
}

extern "C" void kernel_launch(void* const* d_in, const int* in_sizes, int n_in,
                              void* d_out, int out_size, void* d_ws, size_t ws_size,
                              hipStream_t stream) {
  const float* feat  = (const float*)d_in[0];
  const int*   crd   = (const int*)d_in[1];
  const float* jp    = (const float*)d_in[2];
  const float* jg    = (const float*)d_in[3];
  const float* ln1g  = (const float*)d_in[4];
  const float* ln1b  = (const float*)d_in[5];
  const float* W1    = (const float*)d_in[6];
  const float* b1    = (const float*)d_in[7];
  const float* ln2g  = (const float*)d_in[8];
  const float* ln2b  = (const float*)d_in[9];
  const float* W2    = (const float*)d_in[10];
  const float* b2    = (const float*)d_in[11];
  float* out = (float*)d_out;

  unsigned char*  mask = (unsigned char*)d_ws;
  unsigned short* W1f  = (unsigned short*)((char*)d_ws + W1F_OFF);
  unsigned short* W2f  = (unsigned short*)((char*)d_ws + W2F_OFF);

  hipMemsetAsync(mask, 0, (size_t)B_ROWS, stream);
  scatter_mask<<<B_ROWS / 256, 256, 0, stream>>>(crd, mask);
  build_wf<<<560, 512, 0, stream>>>(W1, W2, W1f, W2f);
  actor_main<<<B_ROWS / MTILE, 512, 0, stream>>>(
      feat, mask, jp, jg, ln1g, ln1b, W1f, b1, ln2g, ln2b, W2f, b2, out);
}